// Round 7
// baseline (241.057 us; speedup 1.0000x reference)
//
#include <hip/hip_runtime.h>
#include <stdint.h>
#include <stddef.h>

#define Bsz 16384
#define Hsz 512
#define KG 1536   // K of gemm2 == row stride of A
#define KA 1024   // K of gemm1
#define NT3 48    // gemm2 K tiles of 32

typedef float f32x4 __attribute__((ext_vector_type(4)));
typedef short bf16x8 __attribute__((ext_vector_type(8)));
typedef unsigned short u16;
typedef unsigned int u32;

__device__ __forceinline__ u16 f2bf(float f) {
  union { float f; unsigned u; } v; v.f = f;
  return (u16)((v.u + 0x7fffu + ((v.u >> 16) & 1u)) >> 16);
}
__device__ __forceinline__ float bf2f(u16 h) {
  union { unsigned u; float f; } v; v.u = ((unsigned)h) << 16;
  return v.f;
}
__device__ __forceinline__ float sigm(float x) {
  return 1.0f / (1.0f + __expf(-x));
}
__device__ __forceinline__ float tanh_(float x) {
  x = fminf(fmaxf(x, -15.0f), 15.0f);
  float e = __expf(2.0f * x);
  return (e - 1.0f) / (e + 1.0f);
}

__device__ __forceinline__ void gload_lds16(const u16* g, u16* l) {
  __builtin_amdgcn_global_load_lds(
      (__attribute__((address_space(1))) void*)(g),
      (__attribute__((address_space(3))) void*)(l), 16, 0, 0);
}

__device__ __forceinline__ bf16x8 ds_read128(u32 byte_addr) {
  bf16x8 r;
  asm volatile("ds_read_b128 %0, %1" : "=v"(r) : "v"(byte_addr));
  return r;
}

#define VMCNT(n) asm volatile("s_waitcnt vmcnt(" #n ")" ::: "memory")
#define LGKM(n) { asm volatile("s_waitcnt lgkmcnt(" #n ")" ::: "memory"); \
                  __builtin_amdgcn_sched_barrier(0); }
#define BAR() { asm volatile("" ::: "memory"); __builtin_amdgcn_s_barrier(); \
                asm volatile("" ::: "memory"); }

// ---- cast h_prev | x_t into bf16 A[B][1536] (cols 0..1023) ----
__global__ __launch_bounds__(256) void prep_A_kernel(
    const float* __restrict__ h_prev, const float* __restrict__ x_t,
    u16* __restrict__ A) {
  const int b = blockIdx.x;
  const int q = threadIdx.x;
  const int qq = q & 127;
  const float4* src = (q < 128) ? (const float4*)h_prev : (const float4*)x_t;
  float4 v = src[(size_t)b * 128 + qq];
  ushort4 o;
  o.x = f2bf(v.x); o.y = f2bf(v.y); o.z = f2bf(v.z); o.w = f2bf(v.w);
  *(ushort4*)(A + (size_t)b * KG + (size_t)q * 4) = o;
}

// ---- transpose-cast: in[R][C] fp32 -> out[C][R] bf16 ----
__global__ __launch_bounds__(256) void transpose_cast_kernel(
    const float* __restrict__ in, u16* __restrict__ out, int R, int C) {
  __shared__ float tile[32][33];
  const int c0 = blockIdx.x * 32;
  const int r0 = blockIdx.y * 32;
  const int tx = threadIdx.x;
  const int ty = threadIdx.y;
  #pragma unroll
  for (int i = ty; i < 32; i += 8)
    tile[i][tx] = in[(size_t)(r0 + i) * C + (c0 + tx)];
  __syncthreads();
  #pragma unroll
  for (int i = ty; i < 32; i += 8)
    out[(size_t)(c0 + i) * R + (r0 + tx)] = f2bf(tile[tx][i]);
}

// ---- GEMM1: s = tanh(A[:,0:1024] @ Wst^T + delta*ws_last + bs) -> A[:,1024:1536]
__global__ __launch_bounds__(256, 2) void gemm1_kernel(
    const u16* __restrict__ A, const u16* __restrict__ Wst,
    const float* __restrict__ Ws, const float* __restrict__ bs,
    const float* __restrict__ delta, u16* __restrict__ Aout) {
  __shared__ __attribute__((aligned(16))) u16 Als[128][32];
  __shared__ __attribute__((aligned(16))) u16 Bls[128][32];
  const int t = threadIdx.x;
  const int w = t >> 6, l = t & 63;
  const int bm0 = blockIdx.y * 128;
  const int bn0 = blockIdx.x * 128;
  const int wm = w >> 1, wn = w & 1;

  f32x4 zv = {0.f, 0.f, 0.f, 0.f};
  f32x4 acc[4][4];
  #pragma unroll
  for (int i = 0; i < 4; ++i)
    #pragma unroll
    for (int j = 0; j < 4; ++j) acc[i][j] = zv;

  const int r = t >> 2, q = t & 3;
  const u16* gA0 = A + (size_t)(bm0 + r) * KG + q * 8;
  const u16* gA1 = A + (size_t)(bm0 + 64 + r) * KG + q * 8;
  const u16* gB0 = Wst + (size_t)(bn0 + r) * KA + q * 8;
  const u16* gB1 = Wst + (size_t)(bn0 + 64 + r) * KA + q * 8;
  u16* lA0 = &Als[0][0] + w * 512;
  u16* lA1 = &Als[0][0] + 2048 + w * 512;
  u16* lB0 = &Bls[0][0] + w * 512;
  u16* lB1 = &Bls[0][0] + 2048 + w * 512;

  const int frow = l & 15;
  const int kofs = (l >> 4) * 8;

  for (int kt = 0; kt < KA / 32; ++kt) {
    const int ko = kt * 32;
    gload_lds16(gA0 + ko, lA0);
    gload_lds16(gA1 + ko, lA1);
    gload_lds16(gB0 + ko, lB0);
    gload_lds16(gB1 + ko, lB1);
    __syncthreads();
    bf16x8 af[4], bfv[4];
    #pragma unroll
    for (int mi = 0; mi < 4; ++mi)
      af[mi] = *(const bf16x8*)&Als[wm * 64 + mi * 16 + frow][kofs];
    #pragma unroll
    for (int ni = 0; ni < 4; ++ni)
      bfv[ni] = *(const bf16x8*)&Bls[wn * 64 + ni * 16 + frow][kofs];
    #pragma unroll
    for (int mi = 0; mi < 4; ++mi)
      #pragma unroll
      for (int ni = 0; ni < 4; ++ni)
        acc[mi][ni] = __builtin_amdgcn_mfma_f32_16x16x32_bf16(
            af[mi], bfv[ni], acc[mi][ni], 0, 0, 0);
    __syncthreads();
  }

  #pragma unroll
  for (int ni = 0; ni < 4; ++ni) {
    const int col = bn0 + wn * 64 + ni * 16 + (l & 15);
    const float wsl = Ws[(size_t)1024 * 512 + col];
    const float bsv = bs[col];
    #pragma unroll
    for (int mi = 0; mi < 4; ++mi) {
      #pragma unroll
      for (int rr = 0; rr < 4; ++rr) {
        const int row = bm0 + wm * 64 + mi * 16 + (l >> 4) * 4 + rr;
        const float z = acc[mi][ni][rr] + delta[row] * wsl + bsv;
        Aout[(size_t)row * KG + 1024 + col] = f2bf(tanh_(z));
      }
    }
  }
}

// ---- GEMM2, direct-B design ----
// B fragments load global->VGPR straight from L2 (panel is L2-resident via
// the hb->XCD pinning); only A is LDS-staged (DMA, 3 bufs, 48KB). LDS
// traffic/tile drops 140KB -> 80KB; the 8 A-frag ds_reads are spread in 4
// groups with counted lgkmcnt so the LDS unit overlaps the MFMA stream.
// Per-wave per tile: 5 B-reg loads (t+1) + 2 A-DMA (t+2), VMCNT(2) at top
// (leaves exactly A(t+2)); one raw barrier per tile.
__global__ __launch_bounds__(512, 2) void gemm2_dl(
    const u16* __restrict__ A, const u16* __restrict__ Wgt,
    const float* __restrict__ bg, const float* __restrict__ c_prev,
    float* __restrict__ out) {
  __shared__ __attribute__((aligned(16))) u16 LDSA[3][256 * 32];  // 48 KB

  const int t5 = threadIdx.x;
  const int w = t5 >> 6;
  const int l = t5 & 63;

  const int bid = blockIdx.x;   // 512 blocks = 64 rb x 8 hb
  const int hb = bid & 7;       // h-panel -> pinned XCD (round-robin dispatch)
  const int rb = bid >> 3;
  const int bm0 = rb * 256;
  const int h0 = hb * 64;

  // ---- A staging geometry (all 8 waves, 2 gload_lds each) ----
  // chunked layout with XOR swizzle: idx=(w*128+s*64+l); row=idx>>2;
  // ch=(idx&3)^((idx>>3)&3); LDS linear dest, pre-swizzled global src.
  const u16* gsA0; const u16* gsA1;
  u32 loA0, loA1;
  {
    int idx0 = w * 128 + l;
    int row0 = idx0 >> 2, ch0 = (idx0 & 3) ^ ((idx0 >> 3) & 3);
    gsA0 = A + (size_t)(bm0 + row0) * KG + ch0 * 8;
    loA0 = (u32)(w * 128) * 8;
    int idx1 = w * 128 + 64 + l;
    int row1 = idx1 >> 2, ch1 = (idx1 & 3) ^ ((idx1 >> 3) & 3);
    gsA1 = A + (size_t)(bm0 + row1) * KG + ch1 * 8;
    loA1 = (u32)(w * 128 + 64) * 8;
  }

  const int wm = w >> 2;          // M half (128 rows)
  const int wn = w & 3;           // N group (16 cols within each gate's 64)
  const int frow = l & 15;
  const int kq = l >> 4;

  // ---- B direct-load addresses: lane reads Wgt[g*512+h0+wn*16+frow][k..k+8)
  const u16* barr[5];
  #pragma unroll
  for (int g = 0; g < 5; ++g)
    barr[g] = Wgt + (size_t)(g * Hsz + h0 + wn * 16 + frow) * KG + kq * 8;

  f32x4 zv = {0.f, 0.f, 0.f, 0.f};
  f32x4 acc[8][5];
  #pragma unroll
  for (int mi = 0; mi < 8; ++mi)
    #pragma unroll
    for (int g = 0; g < 5; ++g) acc[mi][g] = zv;

  bf16x8 bfvA[5], bfvB[5];

#define GLOADB(DST) { \
    _Pragma("unroll") \
    for (int g = 0; g < 5; ++g) { \
      asm volatile("global_load_dwordx4 %0, %1, off" \
                   : "=v"(DST[g]) : "v"(barr[g])); \
      barr[g] += 32; \
    } }

  const u32 axor = (u32)((kq ^ ((frow >> 1) & 3)) << 3);
  const u32 abyte = ((u32)(wm * 128 + frow) * 32 + axor) * 2;
  const u32 ldsA0 = (u32)(uintptr_t)&LDSA[0][0];

#define MFMAG(i0, i1, F0, F1, SRC) { \
    __builtin_amdgcn_s_setprio(1); \
    _Pragma("unroll") \
    for (int g = 0; g < 5; ++g) { \
      acc[i0][g] = __builtin_amdgcn_mfma_f32_16x16x32_bf16( \
          F0, SRC[g], acc[i0][g], 0, 0, 0); \
      acc[i1][g] = __builtin_amdgcn_mfma_f32_16x16x32_bf16( \
          F1, SRC[g], acc[i1][g], 0, 0, 0); \
    } \
    __builtin_amdgcn_s_setprio(0); }

  // prologue: A(0)->buf0, B(0)->bfvA, A(1)->buf1  (order matters for VMCNT)
  gload_lds16(gsA0, &LDSA[0][loA0]);
  gload_lds16(gsA1, &LDSA[0][loA1]);
  gsA0 += 32; gsA1 += 32;
  GLOADB(bfvA)
  gload_lds16(gsA0, &LDSA[1][loA0]);
  gload_lds16(gsA1, &LDSA[1][loA1]);
  gsA0 += 32; gsA1 += 32;

  int btA = 0;   // t % 3 (read buffer)
  int btC = 2;   // (t+2) % 3 (DMA target)

#define TILE_BODY(t, CUR, NXT) { \
    if ((t) + 1 < NT3) { VMCNT(2); } else { VMCNT(0); } \
    BAR(); \
    const u32 aB = ldsA0 + (u32)btA * 16384 + abyte; \
    bf16x8 af0 = ds_read128(aB); \
    bf16x8 af1 = ds_read128(aB + 1024); \
    bf16x8 af2 = ds_read128(aB + 2048); \
    bf16x8 af3 = ds_read128(aB + 3072); \
    if ((t) + 1 < NT3) { GLOADB(NXT) } \
    if ((t) + 2 < NT3) { \
      gload_lds16(gsA0, &LDSA[btC][loA0]); \
      gload_lds16(gsA1, &LDSA[btC][loA1]); \
      gsA0 += 32; gsA1 += 32; \
    } \
    bf16x8 af4 = ds_read128(aB + 4096); \
    bf16x8 af5 = ds_read128(aB + 5120); \
    LGKM(4)                 /* af0,af1 ready */ \
    MFMAG(0, 1, af0, af1, CUR) \
    bf16x8 af6 = ds_read128(aB + 6144); \
    bf16x8 af7 = ds_read128(aB + 7168); \
    LGKM(4)                 /* af2,af3 ready */ \
    MFMAG(2, 3, af2, af3, CUR) \
    LGKM(2)                 /* af4,af5 ready */ \
    MFMAG(4, 5, af4, af5, CUR) \
    LGKM(0)                 /* af6,af7 ready */ \
    MFMAG(6, 7, af6, af7, CUR) \
    btA = (btA == 2) ? 0 : btA + 1; \
    btC = (btC == 2) ? 0 : btC + 1; \
  }

  for (int t2 = 0; t2 < NT3; t2 += 2) {
    TILE_BODY(t2, bfvA, bfvB)
    TILE_BODY(t2 + 1, bfvB, bfvA)
  }
#undef TILE_BODY
#undef GLOADB
#undef MFMAG

  const int hc = h0 + wn * 16 + frow;
  const float b_f = bg[hc];
  const float b_i = bg[Hsz + hc];
  const float b_T = bg[2 * Hsz + hc];
  const float b_z = bg[3 * Hsz + hc];
  const float b_o = bg[4 * Hsz + hc];
  #pragma unroll
  for (int mi = 0; mi < 8; ++mi) {
    #pragma unroll
    for (int rr = 0; rr < 4; ++rr) {
      const int row = bm0 + wm * 128 + mi * 16 + kq * 4 + rr;
      const float fg = sigm(acc[mi][0][rr] + b_f);
      const float ig = sigm(acc[mi][1][rr] + b_i);
      const float Tg = sigm(acc[mi][2][rr] + b_T);
      const float zg = tanh_(acc[mi][3][rr] + b_z);
      const float og = sigm(acc[mi][4][rr] + b_o);
      const float cp = c_prev[(size_t)row * Hsz + hc];
      const float st = bf2f(A[(size_t)row * KG + 1024 + hc]);
      const float c = fg * cp + ig * zg + Tg * st;
      const float h = og * tanh_(c);
      out[(size_t)row * Hsz + hc] = h;
      out[(size_t)Bsz * Hsz + (size_t)row * Hsz + hc] = c;
    }
  }
}

extern "C" void kernel_launch(void* const* d_in, const int* in_sizes, int n_in,
                              void* d_out, int out_size, void* d_ws, size_t ws_size,
                              hipStream_t stream) {
  const float* x_t    = (const float*)d_in[0];
  const float* delta  = (const float*)d_in[1];
  const float* h_prev = (const float*)d_in[2];
  const float* c_prev = (const float*)d_in[3];
  const float* Ws     = (const float*)d_in[4];
  const float* bs     = (const float*)d_in[5];
  const float* Wg     = (const float*)d_in[6];
  const float* bg     = (const float*)d_in[7];
  float* out = (float*)d_out;

  char* wsb = (char*)d_ws;
  u16* A   = (u16*)(wsb);                          // [16384][1536] bf16
  u16* Wst = (u16*)(wsb + (size_t)50331648);       // [512][1024]  bf16
  u16* Wgt = (u16*)(wsb + (size_t)51380224);       // [2560][1536] bf16

  prep_A_kernel<<<dim3(16384), dim3(256), 0, stream>>>(h_prev, x_t, A);
  transpose_cast_kernel<<<dim3(16, 32), dim3(32, 8), 0, stream>>>(Ws, Wst, 1024, 512);
  transpose_cast_kernel<<<dim3(80, 48), dim3(32, 8), 0, stream>>>(Wg, Wgt, 1536, 2560);
  gemm1_kernel<<<dim3(4, 128), dim3(256), 0, stream>>>(A, Wst, Ws, bs, delta, A);
  gemm2_dl<<<dim3(512), dim3(512), 0, stream>>>(A, Wgt, bg, c_prev, out);
}